// Round 1
// baseline (292.372 us; speedup 1.0000x reference)
//
#include <hip/hip_runtime.h>

// FineMatchingLoss: C=8192 clusters, K=64 points, B=4 batches, scores (C,65,65).
// Key insight: only ~70 of the 4225 score entries per cluster are labeled
// (sparse gt matches + slack row/col) -> gather instead of streaming 138 MB.

#define KPTS 64
#define NSC  65          // K+1
#define R2   0.01f       // POSITIVE_RADIUS^2

struct WS {
  double bsum[8];
  unsigned long long bcnt[8];
};

__global__ void init_ws(WS* ws) {
  int t = threadIdx.x;
  if (t < 8) { ws->bsum[t] = 0.0; ws->bcnt[t] = 0ULL; }
}

__global__ __launch_bounds__(64) void fine_loss_main(
    const float* __restrict__ ref_pts,    // (C,K,3)
    const float* __restrict__ src_pts,    // (C,K,3)
    const int*   __restrict__ ref_mask,   // (C,K) bool as int32
    const int*   __restrict__ src_mask,   // (C,K) bool as int32
    const float* __restrict__ scores,     // (C,65,65)
    const float* __restrict__ transform,  // (B,4,4)
    const int*   __restrict__ indices,    // (C,)
    const int*   __restrict__ lengths,    // (B,) int32 expected (int64 hedge below)
    WS* __restrict__ ws, int B)
{
  const int c   = blockIdx.x;
  const int tid = threadIdx.x;

  __shared__ float4 sbuf[KPTS];     // (st_x, st_y, st_z, sq_s or +INF)
  __shared__ int    col_any[KPTS];

  // ---- segment lookup: seg = searchsorted(cumsum(lengths), idx, 'right')
  const int idx = indices[c];
  bool bad = false;
  for (int b = 0; b < B; ++b) if (lengths[b] <= 0) bad = true;  // int64 signature
  long long cum = 0; int seg = 0;
  for (int b = 0; b < B; ++b) {
    long long len = bad ? ((const long long*)lengths)[b] : (long long)lengths[b];
    cum += len;
    if (cum <= (long long)idx) seg++;
  }
  if (seg >= B) seg = B - 1;
  if (seg < 0)  seg = 0;

  // ---- transform src point tid: st_i = sum_j R[i][j]*s_j + t_i
  const float* T  = transform + seg * 16;
  const float* sp = src_pts + ((size_t)c * KPTS + tid) * 3;
  const float sx = sp[0], sy = sp[1], sz = sp[2];
  const float stx = T[0]*sx + T[1]*sy + T[2]*sz  + T[3];
  const float sty = T[4]*sx + T[5]*sy + T[6]*sz  + T[7];
  const float stz = T[8]*sx + T[9]*sy + T[10]*sz + T[11];
  const int   sm  = src_mask[(size_t)c * KPTS + tid];
  const float sq_s = stx*stx + sty*sty + stz*stz;
  sbuf[tid] = make_float4(stx, sty, stz, sm ? sq_s : __builtin_inff());
  col_any[tid] = 0;
  __syncthreads();

  // ---- ref point tid
  const float* rp = ref_pts + ((size_t)c * KPTS + tid) * 3;
  const float rx = rp[0], ry = rp[1], rz = rp[2];
  const int   rm = ref_mask[(size_t)c * KPTS + tid];
  const float sq_r = rx*rx + ry*ry + rz*rz;

  const float* sc_row = scores + (size_t)c * (NSC * NSC) + (size_t)tid * NSC;

  float lsum = 0.f;
  int   lcnt = 0;
  bool  row_any = false;

  if (rm) {
    for (int j = 0; j < KPTS; ++j) {
      const float4 s4 = sbuf[j];   // LDS broadcast (all lanes same addr: free)
      const float d = sq_r + s4.w - 2.f * (rx*s4.x + ry*s4.y + rz*s4.z);
      if (d < R2) {                // s4.w == INF for masked-out src -> never true
        lsum -= sc_row[j];         // sparse gather of scores
        lcnt++;
        row_any = true;
        col_any[j] = 1;            // same-value race: benign
      }
    }
    if (!row_any) {                // slack row at column K
      lsum -= sc_row[KPTS];
      lcnt++;
    }
  }
  __syncthreads();

  if (sm && !col_any[tid]) {       // slack col at row K
    lsum -= scores[(size_t)c * (NSC * NSC) + KPTS * NSC + tid];
    lcnt++;
  }

  // ---- wave64 reduce
  for (int off = 32; off >= 1; off >>= 1) {
    lsum += __shfl_xor(lsum, off, 64);
    lcnt += __shfl_xor(lcnt, off, 64);
  }
  if (tid == 0) {
    atomicAdd(&ws->bsum[seg], (double)lsum);
    atomicAdd(&ws->bcnt[seg], (unsigned long long)lcnt);
  }
}

__global__ void finalize_loss(const WS* __restrict__ ws, float* __restrict__ out, int B) {
  double s = 0.0; int n = 0;
  for (int b = 0; b < B; ++b) {
    const unsigned long long cnt = ws->bcnt[b];
    if (cnt > 0) { s += ws->bsum[b] / (double)cnt; n++; }
  }
  out[0] = (n > 0) ? (float)(s / (double)n) : 0.f;
}

extern "C" void kernel_launch(void* const* d_in, const int* in_sizes, int n_in,
                              void* d_out, int out_size, void* d_ws, size_t ws_size,
                              hipStream_t stream) {
  const float* ref_pts   = (const float*)d_in[0];
  const float* src_pts   = (const float*)d_in[1];
  const int*   ref_mask  = (const int*)d_in[2];
  const int*   src_mask  = (const int*)d_in[3];
  const float* scores    = (const float*)d_in[4];
  const float* transform = (const float*)d_in[5];
  const int*   indices   = (const int*)d_in[6];
  const int*   lengths   = (const int*)d_in[7];

  const int C = in_sizes[0] / (KPTS * 3);   // 8192
  const int B = in_sizes[5] / 16;           // 4

  WS* ws = (WS*)d_ws;
  init_ws<<<1, 64, 0, stream>>>(ws);
  fine_loss_main<<<C, 64, 0, stream>>>(ref_pts, src_pts, ref_mask, src_mask,
                                       scores, transform, indices, lengths, ws, B);
  finalize_loss<<<1, 1, 0, stream>>>(ws, (float*)d_out, B);
}

// Round 2
// 208.984 us; speedup vs baseline: 1.3990x; 1.3990x over previous
//
#include <hip/hip_runtime.h>

// FineMatchingLoss: C=8192 clusters, K=64 points, B=4 batches, scores (C,65,65).
// R1 lesson: 8192 waves x 2 device-scope atomics onto 4 hot addresses serialized
// the whole kernel (~135 cy each = 116 us). R2: store per-block partials, reduce
// in a second kernel. No atomics anywhere on the fast path.

#define KPTS 64
#define NSC  65          // K+1
#define R2   0.01f       // POSITIVE_RADIUS^2

struct WS {
  double bsum[8];
  unsigned long long bcnt[8];
};

__global__ void init_ws(WS* ws) {
  int t = threadIdx.x;
  if (t < 8) { ws->bsum[t] = 0.0; ws->bcnt[t] = 0ULL; }
}

__global__ __launch_bounds__(64) void fine_loss_main(
    const float* __restrict__ ref_pts,    // (C,K,3)
    const float* __restrict__ src_pts,    // (C,K,3)
    const int*   __restrict__ ref_mask,   // (C,K) bool as int32
    const int*   __restrict__ src_mask,   // (C,K) bool as int32
    const float* __restrict__ scores,     // (C,65,65)
    const float* __restrict__ transform,  // (B,4,4)
    const int*   __restrict__ indices,    // (C,)
    const int*   __restrict__ lengths,    // (B,) int32 expected (int64 hedge below)
    WS* __restrict__ ws, float4* __restrict__ slots, int use_slots, int B)
{
  const int c   = blockIdx.x;
  const int tid = threadIdx.x;

  __shared__ float4 sbuf[KPTS];     // (st_x, st_y, st_z, sq_s or +INF)

  // ---- segment lookup: seg = searchsorted(cumsum(lengths), idx, 'right')
  const int idx = indices[c];
  bool bad = false;
  for (int b = 0; b < B; ++b) if (lengths[b] <= 0) bad = true;  // int64 signature
  long long cum = 0; int seg = 0;
  for (int b = 0; b < B; ++b) {
    long long len = bad ? ((const long long*)lengths)[b] : (long long)lengths[b];
    cum += len;
    if (cum <= (long long)idx) seg++;
  }
  if (seg >= B) seg = B - 1;
  if (seg < 0)  seg = 0;

  // ---- transform src point tid: st_i = sum_j R[i][j]*s_j + t_i
  const float* T  = transform + seg * 16;
  const float* sp = src_pts + ((size_t)c * KPTS + tid) * 3;
  const float sx = sp[0], sy = sp[1], sz = sp[2];
  const float stx = T[0]*sx + T[1]*sy + T[2]*sz  + T[3];
  const float sty = T[4]*sx + T[5]*sy + T[6]*sz  + T[7];
  const float stz = T[8]*sx + T[9]*sy + T[10]*sz + T[11];
  const int   sm  = src_mask[(size_t)c * KPTS + tid];
  const float sq_s = stx*stx + sty*sty + stz*stz;
  sbuf[tid] = make_float4(stx, sty, stz, sm ? sq_s : __builtin_inff());
  __syncthreads();

  // ---- ref point tid
  const float* rp = ref_pts + ((size_t)c * KPTS + tid) * 3;
  const float rx = rp[0], ry = rp[1], rz = rp[2];
  const int   rm = ref_mask[(size_t)c * KPTS + tid];
  const float sq_r = rx*rx + ry*ry + rz*rz;

  const float* sc_row = scores + (size_t)c * (NSC * NSC) + (size_t)tid * NSC;

  // ---- branchless hit-mask loop (bit j = gt_corr[tid][j])
  unsigned long long hit = 0ULL;
  if (rm) {
    #pragma unroll 8
    for (int j = 0; j < KPTS; ++j) {
      const float4 s4 = sbuf[j];   // LDS broadcast (all lanes same addr: free)
      const float d = sq_r + s4.w - 2.f * (rx*s4.x + ry*s4.y + rz*s4.z);
      hit |= (unsigned long long)(d < R2) << j;  // INF for masked src -> never set
    }
  }

  // column-any = OR of hit masks across the wave (block == 1 wave)
  unsigned long long colmask = hit;
  #pragma unroll
  for (int off = 32; off >= 1; off >>= 1)
    colmask |= __shfl_xor(colmask, off, 64);

  float lsum = 0.f;
  int   lcnt = __popcll(hit);

  // sparse gather of matched scores
  unsigned long long m = hit;
  while (m) {
    const int j = __builtin_ctzll(m);
    m &= m - 1;
    lsum -= sc_row[j];
  }
  if (rm && hit == 0ULL) {          // slack row at column K
    lsum -= sc_row[KPTS];
    lcnt++;
  }
  if (sm && !((colmask >> tid) & 1ULL)) {  // slack col at row K
    lsum -= scores[(size_t)c * (NSC * NSC) + KPTS * NSC + tid];
    lcnt++;
  }

  // ---- wave64 reduce
  #pragma unroll
  for (int off = 32; off >= 1; off >>= 1) {
    lsum += __shfl_xor(lsum, off, 64);
    lcnt += __shfl_xor(lcnt, off, 64);
  }
  if (tid == 0) {
    if (use_slots) {
      slots[c] = make_float4(lsum, __int_as_float(lcnt), __int_as_float(seg), 0.f);
    } else {
      atomicAdd(&ws->bsum[seg], (double)lsum);
      atomicAdd(&ws->bcnt[seg], (unsigned long long)lcnt);
    }
  }
}

__global__ __launch_bounds__(1024) void reduce_partials(
    const float4* __restrict__ slots, int C, int B, float* __restrict__ out)
{
  __shared__ float wsum[16][8];
  __shared__ int   wcnt[16][8];

  float psum[8] = {0.f,0.f,0.f,0.f,0.f,0.f,0.f,0.f};
  int   pcnt[8] = {0,0,0,0,0,0,0,0};

  for (int i = threadIdx.x; i < C; i += 1024) {
    const float4 p = slots[i];
    const int cnt = __float_as_int(p.y);
    const int seg = __float_as_int(p.z);
    #pragma unroll
    for (int s = 0; s < 8; ++s) {        // static indices only (no scratch)
      const bool msk = (seg == s);
      psum[s] += msk ? p.x : 0.f;
      pcnt[s] += msk ? cnt : 0;
    }
  }
  #pragma unroll
  for (int s = 0; s < 8; ++s) {
    #pragma unroll
    for (int off = 32; off >= 1; off >>= 1) {
      psum[s] += __shfl_xor(psum[s], off, 64);
      pcnt[s] += __shfl_xor(pcnt[s], off, 64);
    }
  }
  const int wave = threadIdx.x >> 6;
  const int lane = threadIdx.x & 63;
  if (lane == 0) {
    #pragma unroll
    for (int s = 0; s < 8; ++s) { wsum[wave][s] = psum[s]; wcnt[wave][s] = pcnt[s]; }
  }
  __syncthreads();
  if (threadIdx.x == 0) {
    double acc = 0.0; int n = 0;
    for (int s = 0; s < B; ++s) {
      float ss = 0.f; int cc = 0;
      for (int w = 0; w < 16; ++w) { ss += wsum[w][s]; cc += wcnt[w][s]; }
      if (cc > 0) { acc += (double)ss / (double)cc; n++; }
    }
    out[0] = (n > 0) ? (float)(acc / (double)n) : 0.f;
  }
}

__global__ void finalize_loss(const WS* __restrict__ ws, float* __restrict__ out, int B) {
  double s = 0.0; int n = 0;
  for (int b = 0; b < B; ++b) {
    const unsigned long long cnt = ws->bcnt[b];
    if (cnt > 0) { s += ws->bsum[b] / (double)cnt; n++; }
  }
  out[0] = (n > 0) ? (float)(s / (double)n) : 0.f;
}

extern "C" void kernel_launch(void* const* d_in, const int* in_sizes, int n_in,
                              void* d_out, int out_size, void* d_ws, size_t ws_size,
                              hipStream_t stream) {
  const float* ref_pts   = (const float*)d_in[0];
  const float* src_pts   = (const float*)d_in[1];
  const int*   ref_mask  = (const int*)d_in[2];
  const int*   src_mask  = (const int*)d_in[3];
  const float* scores    = (const float*)d_in[4];
  const float* transform = (const float*)d_in[5];
  const int*   indices   = (const int*)d_in[6];
  const int*   lengths   = (const int*)d_in[7];

  const int C = in_sizes[0] / (KPTS * 3);   // 8192
  const int B = in_sizes[5] / 16;           // 4

  WS*     ws    = (WS*)d_ws;
  float4* slots = (float4*)((char*)d_ws + 256);
  const int use_slots = (ws_size >= (size_t)(256 + (size_t)C * 16)) ? 1 : 0;

  if (!use_slots) init_ws<<<1, 64, 0, stream>>>(ws);
  fine_loss_main<<<C, 64, 0, stream>>>(ref_pts, src_pts, ref_mask, src_mask,
                                       scores, transform, indices, lengths,
                                       ws, slots, use_slots, B);
  if (use_slots) reduce_partials<<<1, 1024, 0, stream>>>(slots, C, B, (float*)d_out);
  else           finalize_loss<<<1, 1, 0, stream>>>(ws, (float*)d_out, B);
}

// Round 3
// 206.569 us; speedup vs baseline: 1.4154x; 1.0117x over previous
//
#include <hip/hip_runtime.h>

// FineMatchingLoss: C=8192 clusters, K=64 points, B=4 batches, scores (C,65,65).
// R1: hot-address double atomics serialized everything (116 us).
// R2: per-block partial slots + reduce kernel -> ~33 us of kernel time;
//     remaining dur_us is dominated by the harness's 528 MB 0xAA ws re-poison.
// R3: pack 4 clusters (4 waves) per 256-thread block to double wave residency
//     (49% -> ~full occupancy) and hide the uncoalesced score-gather latency.

#define KPTS 64
#define NSC  65          // K+1
#define R2   0.01f       // POSITIVE_RADIUS^2

struct WS {
  double bsum[8];
  unsigned long long bcnt[8];
};

__global__ void init_ws(WS* ws) {
  int t = threadIdx.x;
  if (t < 8) { ws->bsum[t] = 0.0; ws->bcnt[t] = 0ULL; }
}

__global__ __launch_bounds__(256) void fine_loss_main(
    const float* __restrict__ ref_pts,    // (C,K,3)
    const float* __restrict__ src_pts,    // (C,K,3)
    const int*   __restrict__ ref_mask,   // (C,K) bool as int32
    const int*   __restrict__ src_mask,   // (C,K) bool as int32
    const float* __restrict__ scores,     // (C,65,65)
    const float* __restrict__ transform,  // (B,4,4)
    const int*   __restrict__ indices,    // (C,)
    const int*   __restrict__ lengths,    // (B,) int32 expected (int64 hedge below)
    WS* __restrict__ ws, float4* __restrict__ slots, int use_slots, int B, int C)
{
  const int wave = threadIdx.x >> 6;            // 4 waves/block, 1 cluster/wave
  const int lane = threadIdx.x & 63;
  const int c    = blockIdx.x * 4 + wave;

  __shared__ float4 sbuf[4][KPTS];   // (st_x, st_y, st_z, sq_s or +INF)

  if (c < C) {
    // ---- segment lookup: seg = searchsorted(cumsum(lengths), idx, 'right')
    const int idx = indices[c];
    bool bad = false;
    for (int b = 0; b < B; ++b) if (lengths[b] <= 0) bad = true;  // int64 signature
    long long cum = 0; int seg = 0;
    for (int b = 0; b < B; ++b) {
      long long len = bad ? ((const long long*)lengths)[b] : (long long)lengths[b];
      cum += len;
      if (cum <= (long long)idx) seg++;
    }
    if (seg >= B) seg = B - 1;
    if (seg < 0)  seg = 0;

    // ---- transform src point `lane`: st_i = sum_j R[i][j]*s_j + t_i
    const float* T  = transform + seg * 16;
    const float* sp = src_pts + ((size_t)c * KPTS + lane) * 3;
    const float sx = sp[0], sy = sp[1], sz = sp[2];
    const float stx = T[0]*sx + T[1]*sy + T[2]*sz  + T[3];
    const float sty = T[4]*sx + T[5]*sy + T[6]*sz  + T[7];
    const float stz = T[8]*sx + T[9]*sy + T[10]*sz + T[11];
    const int   sm  = src_mask[(size_t)c * KPTS + lane];
    const float sq_s = stx*stx + sty*sty + stz*stz;
    sbuf[wave][lane] = make_float4(stx, sty, stz, sm ? sq_s : __builtin_inff());
    __syncthreads();

    // ---- ref point `lane`
    const float* rp = ref_pts + ((size_t)c * KPTS + lane) * 3;
    const float rx = rp[0], ry = rp[1], rz = rp[2];
    const int   rm = ref_mask[(size_t)c * KPTS + lane];
    const float sq_r = rx*rx + ry*ry + rz*rz;

    const float* sc_row = scores + (size_t)c * (NSC * NSC) + (size_t)lane * NSC;

    // ---- branchless hit-mask loop (bit j = gt_corr[lane][j])
    unsigned long long hit = 0ULL;
    if (rm) {
      #pragma unroll 8
      for (int j = 0; j < KPTS; ++j) {
        const float4 s4 = sbuf[wave][j];  // LDS broadcast (uniform addr: free)
        const float d = sq_r + s4.w - 2.f * (rx*s4.x + ry*s4.y + rz*s4.z);
        hit |= (unsigned long long)(d < R2) << j;  // INF for masked src -> never
      }
    }

    // column-any = OR of hit masks across the wave (one cluster == one wave)
    unsigned long long colmask = hit;
    #pragma unroll
    for (int off = 32; off >= 1; off >>= 1)
      colmask |= __shfl_xor(colmask, off, 64);

    float lsum = 0.f;
    int   lcnt = __popcll(hit);

    // sparse gather of matched scores
    unsigned long long m = hit;
    while (m) {
      const int j = __builtin_ctzll(m);
      m &= m - 1;
      lsum -= sc_row[j];
    }
    if (rm && hit == 0ULL) {          // slack row at column K
      lsum -= sc_row[KPTS];
      lcnt++;
    }
    if (sm && !((colmask >> lane) & 1ULL)) {  // slack col at row K
      lsum -= scores[(size_t)c * (NSC * NSC) + KPTS * NSC + lane];
      lcnt++;
    }

    // ---- wave64 reduce
    #pragma unroll
    for (int off = 32; off >= 1; off >>= 1) {
      lsum += __shfl_xor(lsum, off, 64);
      lcnt += __shfl_xor(lcnt, off, 64);
    }
    if (lane == 0) {
      if (use_slots) {
        slots[c] = make_float4(lsum, __int_as_float(lcnt), __int_as_float(seg), 0.f);
      } else {
        atomicAdd(&ws->bsum[seg], (double)lsum);
        atomicAdd(&ws->bcnt[seg], (unsigned long long)lcnt);
      }
    }
  }
}

__global__ __launch_bounds__(1024) void reduce_partials(
    const float4* __restrict__ slots, int C, int B, float* __restrict__ out)
{
  __shared__ float wsum[16][8];
  __shared__ int   wcnt[16][8];

  float psum[8] = {0.f,0.f,0.f,0.f,0.f,0.f,0.f,0.f};
  int   pcnt[8] = {0,0,0,0,0,0,0,0};

  for (int i = threadIdx.x; i < C; i += 1024) {
    const float4 p = slots[i];
    const int cnt = __float_as_int(p.y);
    const int seg = __float_as_int(p.z);
    #pragma unroll
    for (int s = 0; s < 8; ++s) {        // static indices only (no scratch)
      const bool msk = (seg == s);
      psum[s] += msk ? p.x : 0.f;
      pcnt[s] += msk ? cnt : 0;
    }
  }
  #pragma unroll
  for (int s = 0; s < 8; ++s) {
    #pragma unroll
    for (int off = 32; off >= 1; off >>= 1) {
      psum[s] += __shfl_xor(psum[s], off, 64);
      pcnt[s] += __shfl_xor(pcnt[s], off, 64);
    }
  }
  const int wave = threadIdx.x >> 6;
  const int lane = threadIdx.x & 63;
  if (lane == 0) {
    #pragma unroll
    for (int s = 0; s < 8; ++s) { wsum[wave][s] = psum[s]; wcnt[wave][s] = pcnt[s]; }
  }
  __syncthreads();
  if (threadIdx.x == 0) {
    double acc = 0.0; int n = 0;
    for (int s = 0; s < B; ++s) {
      float ss = 0.f; int cc = 0;
      for (int w = 0; w < 16; ++w) { ss += wsum[w][s]; cc += wcnt[w][s]; }
      if (cc > 0) { acc += (double)ss / (double)cc; n++; }
    }
    out[0] = (n > 0) ? (float)(acc / (double)n) : 0.f;
  }
}

__global__ void finalize_loss(const WS* __restrict__ ws, float* __restrict__ out, int B) {
  double s = 0.0; int n = 0;
  for (int b = 0; b < B; ++b) {
    const unsigned long long cnt = ws->bcnt[b];
    if (cnt > 0) { s += ws->bsum[b] / (double)cnt; n++; }
  }
  out[0] = (n > 0) ? (float)(s / (double)n) : 0.f;
}

extern "C" void kernel_launch(void* const* d_in, const int* in_sizes, int n_in,
                              void* d_out, int out_size, void* d_ws, size_t ws_size,
                              hipStream_t stream) {
  const float* ref_pts   = (const float*)d_in[0];
  const float* src_pts   = (const float*)d_in[1];
  const int*   ref_mask  = (const int*)d_in[2];
  const int*   src_mask  = (const int*)d_in[3];
  const float* scores    = (const float*)d_in[4];
  const float* transform = (const float*)d_in[5];
  const int*   indices   = (const int*)d_in[6];
  const int*   lengths   = (const int*)d_in[7];

  const int C = in_sizes[0] / (KPTS * 3);   // 8192
  const int B = in_sizes[5] / 16;           // 4

  WS*     ws    = (WS*)d_ws;
  float4* slots = (float4*)((char*)d_ws + 256);
  const int use_slots = (ws_size >= (size_t)(256 + (size_t)C * 16)) ? 1 : 0;

  if (!use_slots) init_ws<<<1, 64, 0, stream>>>(ws);
  const int nblk = (C + 3) / 4;
  fine_loss_main<<<nblk, 256, 0, stream>>>(ref_pts, src_pts, ref_mask, src_mask,
                                           scores, transform, indices, lengths,
                                           ws, slots, use_slots, B, C);
  if (use_slots) reduce_partials<<<1, 1024, 0, stream>>>(slots, C, B, (float*)d_out);
  else           finalize_loss<<<1, 1, 0, stream>>>(ws, (float*)d_out, B);
}